// Round 3
// 19490.637 us; speedup vs baseline: 1.2470x; 1.2470x over previous
//
#include <hip/hip_runtime.h>
#include <hip/hip_bf16.h>

#define T_STEPS 2048
#define BATCH   64
#define HID     512
#define NBG 2      // batch groups (32 rows each)
#define NCG 16     // column-chunk groups (32 cols each)
#define CHUNK 32

typedef unsigned short u16;
typedef unsigned int u32;
typedef unsigned long long u64;
typedef __attribute__((ext_vector_type(4))) float f32x4;
typedef __attribute__((ext_vector_type(8))) short bf16x8;

static __device__ __forceinline__ u16 f2bf(float f) {
  union { float f; unsigned u; } v; v.f = f;
  unsigned u = v.u;
  return (u16)((u + 0x7fffu + ((u >> 16) & 1u)) >> 16);
}
static __device__ __forceinline__ float bf2f(u16 h) {
  union { unsigned u; float f; } v; v.u = ((unsigned)h) << 16; return v.f;
}

// relaxed agent-scope 64-bit accessors: per-instruction coherence (bypass
// non-coherent caches), no cache-maintenance instructions. Tag travels in
// the same atomic word as the payload -> single round trip, no flags.
static __device__ __forceinline__ void st_rlx64(u64* p, u64 v) {
  __hip_atomic_store(p, v, __ATOMIC_RELAXED, __HIP_MEMORY_SCOPE_AGENT);
}
static __device__ __forceinline__ u64 ld_rlx64(const u64* p) {
  return __hip_atomic_load(p, __ATOMIC_RELAXED, __HIP_MEMORY_SCOPE_AGENT);
}

// ---------------- zero the exchange buffers (replaces hipMemsetAsync) ----------------
__global__ __launch_bounds__(256) void zero_exch(u64* __restrict__ p) {
  p[(size_t)blockIdx.x * 256 + threadIdx.x] = 0ull;   // grid covers 65536 words exactly
}

// ---------------- weight fp32 -> bf16 ----------------
__global__ __launch_bounds__(256) void cvt_weights(
    const float* __restrict__ wxf, const float* __restrict__ wxh,
    const float* __restrict__ whf, const float* __restrict__ whh,
    u16* __restrict__ o_wxf, u16* __restrict__ o_wxh,
    u16* __restrict__ o_whf, u16* __restrict__ o_whh) {
  int i = blockIdx.x * 256 + threadIdx.x;   // grid covers 512*512 exactly
  o_wxf[i] = f2bf(wxf[i]);
  o_wxh[i] = f2bf(wxh[i]);
  o_whf[i] = f2bf(whf[i]);
  o_whh[i] = f2bf(whh[i]);
}

// ---------------- xf/xh = x @ Wx^T + b  (bf16 out) ----------------
__global__ __launch_bounds__(256) void proj_gemm(
    const float* __restrict__ x,
    const u16* __restrict__ wxf, const u16* __restrict__ wxh,
    const float* __restrict__ b_f, const float* __restrict__ b_h,
    u16* __restrict__ xfo, u16* __restrict__ xho) {
  const int bid = blockIdx.x;
  const int mbase = (bid >> 4) * 64;
  const int nbase = (bid & 15) * 64;
  const int tid = threadIdx.x;
  const int lane = tid & 63, wv = tid >> 6;
  const int l15 = lane & 15, lhi = lane >> 4;
  __shared__ u16 a_lds[64 * 48];

  const u16* bptr[4];
#pragma unroll
  for (int ntt = 0; ntt < 4; ++ntt) {
    int n = nbase + ntt * 16 + l15;
    bptr[ntt] = (n < 512) ? (wxf + (size_t)n * 512) : (wxh + (size_t)(n - 512) * 512);
  }
  const int arow = tid >> 2;
  const int akq = (tid & 3) * 8;
  const float* asrc = x + (size_t)(mbase + arow) * 512 + akq;

  f32x4 acc[4];
#pragma unroll
  for (int i = 0; i < 4; ++i) acc[i] = (f32x4){0.f, 0.f, 0.f, 0.f};

  for (int kk = 0; kk < 512; kk += 32) {
    float4 v0 = *(const float4*)(asrc + kk);
    float4 v1 = *(const float4*)(asrc + kk + 4);
    u16* dst = &a_lds[arow * 48 + akq];
    dst[0] = f2bf(v0.x); dst[1] = f2bf(v0.y); dst[2] = f2bf(v0.z); dst[3] = f2bf(v0.w);
    dst[4] = f2bf(v1.x); dst[5] = f2bf(v1.y); dst[6] = f2bf(v1.z); dst[7] = f2bf(v1.w);
    __syncthreads();
    bf16x8 a = *(const bf16x8*)&a_lds[(wv * 16 + l15) * 48 + lhi * 8];
#pragma unroll
    for (int ntt = 0; ntt < 4; ++ntt) {
      bf16x8 b = *(const bf16x8*)(bptr[ntt] + kk + lhi * 8);
      acc[ntt] = __builtin_amdgcn_mfma_f32_16x16x32_bf16(a, b, acc[ntt], 0, 0, 0);
    }
    __syncthreads();
  }
#pragma unroll
  for (int ntt = 0; ntt < 4; ++ntt) {
    int n = nbase + ntt * 16 + l15;
    float bias = (n < 512) ? b_f[n] : b_h[n - 512];
    u16* op = (n < 512) ? (xfo + n) : (xho + (n - 512));
#pragma unroll
    for (int q = 0; q < 4; ++q) {
      int row = mbase + wv * 16 + lhi * 4 + q;
      op[(size_t)row * 512] = f2bf(acc[ntt][q] + bias);
    }
  }
}

// Stage one exchange (32 rows x 512 cols, tagged u64 words) into h_lds.
// Issues all 32 loads pipelined, then re-polls only stale words.
// Tag check is '>= tag' (monotone tags): within a run this is equivalent to
// '== tag' (a writer provably cannot lap a peer's slot), but it can never
// spin forever on stale buffer state from an un-reset replay.
// SYNC_BEFORE_LDS: barrier between poll-completion and the LDS overwrite
// (needed when other threads may still be reading h_lds's previous contents).
template <bool SYNC_BEFORE_LDS>
static __device__ __forceinline__ void stage_exchange(
    const u64* __restrict__ src0, u32 tag, int tid, u16* h_lds) {
  u64 w[32];
#pragma unroll
  for (int j = 0; j < 8; ++j) {
    int s = tid + (j << 8);
    const u64* p = src0 + ((s >> 6) << 8) + ((s & 63) << 2);
#pragma unroll
    for (int k = 0; k < 4; ++k) w[j * 4 + k] = ld_rlx64(p + k);
  }
  for (;;) {
    bool ok = true;
#pragma unroll
    for (int j = 0; j < 8; ++j) {
      int s = tid + (j << 8);
      const u64* p = src0 + ((s >> 6) << 8) + ((s & 63) << 2);
#pragma unroll
      for (int k = 0; k < 4; ++k) {
        if ((u32)(w[j * 4 + k] >> 32) < tag) { w[j * 4 + k] = ld_rlx64(p + k); ok = false; }
      }
    }
    if (ok) break;
    __builtin_amdgcn_s_sleep(1);   // light backoff: cut coherent-fabric hammering
  }
  if (SYNC_BEFORE_LDS) __syncthreads();
#pragma unroll
  for (int j = 0; j < 8; ++j) {
    int s = tid + (j << 8);
    int r = s >> 6, g8 = s & 63;
    int slot = (g8 + r) & 63;
    u32* d = (u32*)&h_lds[r * 512 + slot * 8];
    d[0] = (u32)w[j * 4 + 0]; d[1] = (u32)w[j * 4 + 1];
    d[2] = (u32)w[j * 4 + 2]; d[3] = (u32)w[j * 4 + 3];
  }
}

// ---------------- persistent recurrent scan ----------------
__global__ __launch_bounds__(256) void mgu_scan(
    const float* __restrict__ h0,
    const u16* __restrict__ whf, const u16* __restrict__ whh,
    const u16* __restrict__ xf, const u16* __restrict__ xh,
    u64* hexch, u64* gexch,
    float* __restrict__ y, float* __restrict__ hfin) {
  const int bg = blockIdx.x / NCG;
  const int cg = blockIdx.x % NCG;
  const int tid = threadIdx.x;
  const int lane = tid & 63;
  const int wv = tid >> 6;
  const int l15 = lane & 15, lhi = lane >> 4;
  const int mt = wv & 1, nt = wv >> 1;

  __shared__ u16 w_lds[2 * 2 * 16 * 64 * 8];  // 64 KB B-frags
  __shared__ u16 h_lds[32 * 512];             // 32 KB A operand, rotated groups

  for (int s = tid; s < 4096; s += 256) {
    int ln = s & 63;
    int kb = (s >> 6) & 15;
    int wnt = (s >> 10) & 1;
    int which = s >> 11;
    int n = cg * CHUNK + wnt * 16 + (ln & 15);
    int k = kb * 32 + (ln >> 4) * 8;
    const u16* src = (which ? whh : whf) + (size_t)n * 512 + k;
    *(bf16x8*)&w_lds[(((which * 2 + wnt) * 16 + kb) * 64 + ln) * 8] = *(const bf16x8*)src;
  }

  const int rowbase = bg * 32;
  const int r_a = mt * 16 + l15;
  const int cloc = nt * 16 + l15;
  const int gcol = cg * CHUNK + cloc;

  for (int t = 0; t < T_STEPS; ++t) {
    // ---- prefetch x-projections for this step (off the post-GEMM path) ----
    const u16* xfp = xf + ((size_t)t * BATCH + rowbase) * 512 + gcol;
    const u16* xhp = xh + ((size_t)t * BATCH + rowbase) * 512 + gcol;
    u16 xfv[4], xhv[4];
#pragma unroll
    for (int q = 0; q < 4; ++q) {
      int r = mt * 16 + lhi * 4 + q;
      xfv[q] = xfp[(size_t)r * 512];
      xhv[q] = xhp[(size_t)r * 512];
    }

    // ---- stage h into LDS ----
    if (t == 0) {
      for (int s = tid; s < 2048; s += 256) {
        int r = s >> 6, g8 = s & 63;
        int slot = (g8 + r) & 63;
        const float* src = h0 + (size_t)(rowbase + r) * 512 + g8 * 8;
        u16* dst = &h_lds[r * 512 + slot * 8];
#pragma unroll
        for (int j = 0; j < 8; ++j) dst[j] = f2bf(src[j]);
      }
    } else {
      // h(t) written by peers at end of step t-1 with tag t, slot (t-1)&1.
      // Prior barrier (post-GEMM2) already separated h_lds readers.
      const u64* src0 = hexch + (size_t)((t - 1) & 1) * (BATCH * 256) + (size_t)rowbase * 256;
      stage_exchange<false>(src0, (u32)t, tid, h_lds);
    }
    __syncthreads();

    // ---- GEMM 1: P = h @ Wh_f_chunk^T ----
    f32x4 acc = {0.f, 0.f, 0.f, 0.f};
#pragma unroll
    for (int kb = 0; kb < 16; ++kb) {
      int slot = (kb * 4 + lhi + r_a) & 63;
      bf16x8 a = *(const bf16x8*)&h_lds[r_a * 512 + slot * 8];
      bf16x8 b = *(const bf16x8*)&w_lds[((nt * 16 + kb) * 64 + lane) * 8];
      acc = __builtin_amdgcn_mfma_f32_16x16x32_bf16(a, b, acc, 0, 0, 0);
    }

    float fv[4], hv[4];
#pragma unroll
    for (int q = 0; q < 4; ++q) {
      int r = mt * 16 + lhi * 4 + q;
      float pre = acc[q] + bf2f(xfv[q]);
      float f = 1.f / (1.f + __expf(-pre));
      int slot2 = ((gcol >> 3) + r) & 63;
      float h = bf2f(h_lds[r * 512 + slot2 * 8 + (gcol & 7)]);
      fv[q] = f; hv[q] = h;
    }
    // store tagged g = f*h (fire-and-forget; no drain, no flag)
    {
      u64* gx = gexch + (size_t)(t & 1) * (BATCH * 256) + (size_t)rowbase * 256;
      const u32 tg = (u32)(t + 1);
#pragma unroll
      for (int q = 0; q < 4; ++q) {
        float g = fv[q] * hv[q];
        float og = __shfl_xor(g, 1);
        if (!(l15 & 1)) {
          int r = mt * 16 + lhi * 4 + q;
          u64 wv_ = (u64)((u32)f2bf(g) | ((u32)f2bf(og) << 16)) | ((u64)tg << 32);
          st_rlx64(gx + r * 256 + (gcol >> 1), wv_);
        }
      }
    }

    // ---- stage g (poll in regs, barrier inside before LDS overwrite) ----
    {
      const u64* src0 = gexch + (size_t)(t & 1) * (BATCH * 256) + (size_t)rowbase * 256;
      stage_exchange<true>(src0, (u32)(t + 1), tid, h_lds);
    }
    __syncthreads();

    // ---- GEMM 2: Q = g @ Wh_h_chunk^T ----
    f32x4 acc2 = {0.f, 0.f, 0.f, 0.f};
#pragma unroll
    for (int kb = 0; kb < 16; ++kb) {
      int slot = (kb * 4 + lhi + r_a) & 63;
      bf16x8 a = *(const bf16x8*)&h_lds[r_a * 512 + slot * 8];
      bf16x8 b = *(const bf16x8*)&w_lds[(((2 + nt) * 16 + kb) * 64 + lane) * 8];
      acc2 = __builtin_amdgcn_mfma_f32_16x16x32_bf16(a, b, acc2, 0, 0, 0);
    }
    __syncthreads();   // all h_lds(g) reads done; next iteration may overwrite

    // ---- epilogue: h_new, tagged store first, then y/hfin ----
    float hnv[4];
#pragma unroll
    for (int q = 0; q < 4; ++q) {
      float pre = acc2[q] + bf2f(xhv[q]);
      float e = __expf(-2.f * fabsf(pre));
      float ht = copysignf((1.f - e) / (1.f + e), pre);
      hnv[q] = (1.f - fv[q]) * hv[q] + fv[q] * ht;
    }
    {
      u64* hx = hexch + (size_t)(t & 1) * (BATCH * 256) + (size_t)rowbase * 256;
      const u32 tg = (u32)(t + 1);
#pragma unroll
      for (int q = 0; q < 4; ++q) {
        float hn = hnv[q];
        float oh = __shfl_xor(hn, 1);
        if (!(l15 & 1)) {
          int r = mt * 16 + lhi * 4 + q;
          u64 wv_ = (u64)((u32)f2bf(hn) | ((u32)f2bf(oh) << 16)) | ((u64)tg << 32);
          st_rlx64(hx + r * 256 + (gcol >> 1), wv_);
        }
      }
    }
    float* yp = y + ((size_t)t * BATCH + rowbase) * 512 + gcol;
#pragma unroll
    for (int q = 0; q < 4; ++q) {
      int r = mt * 16 + lhi * 4 + q;
      yp[(size_t)r * 512] = hnv[q];
    }
    if (t == T_STEPS - 1) {
#pragma unroll
      for (int q = 0; q < 4; ++q) {
        int r = mt * 16 + lhi * 4 + q;
        hfin[(size_t)(rowbase + r) * 512 + gcol] = hnv[q];
      }
    }
  }
}

extern "C" void kernel_launch(void* const* d_in, const int* in_sizes, int n_in,
                              void* d_out, int out_size, void* d_ws, size_t ws_size,
                              hipStream_t stream) {
  const float* x   = (const float*)d_in[0];
  const float* h0  = (const float*)d_in[1];
  const float* Wxf = (const float*)d_in[2];
  const float* Whf = (const float*)d_in[3];
  const float* bf_ = (const float*)d_in[4];
  const float* Wxh = (const float*)d_in[5];
  const float* Whh = (const float*)d_in[6];
  const float* bh_ = (const float*)d_in[7];
  float* y = (float*)d_out;
  float* hfin = y + (size_t)T_STEPS * BATCH * HID;

  char* ws = (char*)d_ws;
  u16* wxf_b = (u16*)(ws + 0);
  u16* wxh_b = (u16*)(ws + 524288);
  u16* whf_b = (u16*)(ws + 1048576);
  u16* whh_b = (u16*)(ws + 1572864);
  u64* hexch = (u64*)(ws + 2097152);   // 2 slots * 64 rows * 256 words * 8B = 256KB
  u64* gexch = (u64*)(ws + 2359296);   // 256KB
  u16* xfw   = (u16*)(ws + 2621440);
  u16* xhw   = (u16*)(ws + 2621440 + 134217728);

  // zero exchange tags with a device kernel (graph-capture-safe; no memset API)
  hipLaunchKernelGGL(zero_exch, dim3(256), dim3(256), 0, stream, hexch);

  hipLaunchKernelGGL(cvt_weights, dim3(1024), dim3(256), 0, stream,
                     Wxf, Wxh, Whf, Whh, wxf_b, wxh_b, whf_b, whh_b);
  hipLaunchKernelGGL(proj_gemm, dim3(32768), dim3(256), 0, stream,
                     x, wxf_b, wxh_b, bf_, bh_, xfw, xhw);
  hipLaunchKernelGGL(mgu_scan, dim3(NBG * NCG), dim3(256), 0, stream,
                     h0, whf_b, whh_b, xfw, xhw, hexch, gexch, y, hfin);
}